// Round 4
// baseline (367.414 us; speedup 1.0000x reference)
//
#include <hip/hip_runtime.h>

#define BLOCK 256
#define CAP 24   // max stored in-edges per node; in-deg ~ Poisson(5), P(>24) ~ 1e-11

typedef float f2v __attribute__((ext_vector_type(2)));   // native vec types for nontemporal builtins
typedef int   i4v __attribute__((ext_vector_type(4)));
typedef float f4v __attribute__((ext_vector_type(4)));

// ---------- mark selected nodes into a BITMASK (50 KB; line covers 2048 nodes) ----------
__global__ void mark_kernel(const int* __restrict__ sel, unsigned int* __restrict__ bits,
                            int n_up) {
    int u = blockIdx.x * blockDim.x + threadIdx.x;
    if (u < n_up) {
        int v = sel[u];
        atomicOr(&bits[v >> 5], 1u << (v & 31));
    }
}

// ---------- fill node-keyed slots, edge-parallel, vectorized ----------
template <int KK>
__global__ void fill_kernel(const int* __restrict__ nidx, const float* __restrict__ wdown,
                            const unsigned int* __restrict__ bits,
                            int* __restrict__ cursor, int2* __restrict__ slots, int E) {
    int i4 = blockIdx.x * blockDim.x + threadIdx.x;
    int base = i4 * 4;
    if (base + 3 < E) {
        // streamed once, no reuse -> nontemporal keeps L2 for bitmask/cursor
        i4v mm = __builtin_nontemporal_load((const i4v*)nidx + i4);
        f4v ww = __builtin_nontemporal_load((const f4v*)wdown + i4);
        // issue the 4 independent bitmask word loads up front
        unsigned int b0 = (mm[0] >= 0) ? bits[mm[0] >> 5] : 0u;
        unsigned int b1 = (mm[1] >= 0) ? bits[mm[1] >> 5] : 0u;
        unsigned int b2 = (mm[2] >= 0) ? bits[mm[2] >> 5] : 0u;
        unsigned int b3 = (mm[3] >= 0) ? bits[mm[3] >> 5] : 0u;
        {
            int m = mm[0];
            if ((b0 >> (m & 31)) & 1u) {
                int n = (base + 0) / KK;  // compile-time KK -> magic mul
                int c = atomicAdd(&cursor[m], 1);
                if (c < CAP) slots[(size_t)m * CAP + c] = make_int2(n, __float_as_int(ww[0]));
            }
        }
        {
            int m = mm[1];
            if ((b1 >> (m & 31)) & 1u) {
                int n = (base + 1) / KK;
                int c = atomicAdd(&cursor[m], 1);
                if (c < CAP) slots[(size_t)m * CAP + c] = make_int2(n, __float_as_int(ww[1]));
            }
        }
        {
            int m = mm[2];
            if ((b2 >> (m & 31)) & 1u) {
                int n = (base + 2) / KK;
                int c = atomicAdd(&cursor[m], 1);
                if (c < CAP) slots[(size_t)m * CAP + c] = make_int2(n, __float_as_int(ww[2]));
            }
        }
        {
            int m = mm[3];
            if ((b3 >> (m & 31)) & 1u) {
                int n = (base + 3) / KK;
                int c = atomicAdd(&cursor[m], 1);
                if (c < CAP) slots[(size_t)m * CAP + c] = make_int2(n, __float_as_int(ww[3]));
            }
        }
    } else if (base < E) {
        for (int e = base; e < E; ++e) {
            int m = nidx[e];
            if (m >= 0 && ((bits[m >> 5] >> (m & 31)) & 1u)) {
                int n = e / KK;
                int c = atomicAdd(&cursor[m], 1);
                if (c < CAP) slots[(size_t)m * CAP + c] = make_int2(n, __float_as_int(wdown[e]));
            }
        }
    }
}

// generic-K fallback (runtime division)
__global__ void fill_generic_kernel(const int* __restrict__ nidx, const float* __restrict__ wdown,
                                    const unsigned int* __restrict__ bits,
                                    int* __restrict__ cursor, int2* __restrict__ slots,
                                    int E, int K) {
    int e = blockIdx.x * blockDim.x + threadIdx.x;
    if (e >= E) return;
    int m = nidx[e];
    if (m >= 0 && ((bits[m >> 5] >> (m & 31)) & 1u)) {
        int n = e / K;
        int c = atomicAdd(&cursor[m], 1);
        if (c < CAP) slots[(size_t)m * CAP + c] = make_int2(n, __float_as_int(wdown[e]));
    }
}

// ---------- gather + normalize ----------
// ONE row per wave64; 64 lanes x float2 = 512B per feature row (fully coalesced).
// r and m are wave-uniform (readfirstlane) -> sel/cursor/slots become SCALAR loads:
// slot pairs live in SGPRs, broadcast to FMAs for free, no shuffles at all.
// cursor + chunk-0 slot loads are issued in parallel (peeled, CAP-bounds-safe).
__global__ __launch_bounds__(256, 8)
void gather_kernel(const float2* __restrict__ feat2, const int2* __restrict__ slots,
                   const int* __restrict__ cursor, const int* __restrict__ sel,
                   float2* __restrict__ out2, int n_up) {
    int gid = blockIdx.x * blockDim.x + threadIdx.x;
    int r = __builtin_amdgcn_readfirstlane(gid >> 6);   // one row per wave
    int l = threadIdx.x & 63;
    if (r >= n_up) return;                               // wave-uniform exit

    int m = __builtin_amdgcn_readfirstlane(sel[r]);
    const int2* __restrict__ srow = slots + (size_t)m * CAP;

    int deg = cursor[m];                                 // scalar load, in flight...
    int nn0[8];
    float w0[8];
#pragma unroll
    for (int t = 0; t < 8; ++t) {                        // ...parallel with slot chunk 0
        int2 pr = srow[t];                               // always in-bounds (CAP=24)
        nn0[t] = pr.x;
        w0[t] = __int_as_float(pr.y);
    }
    if (deg > CAP) deg = CAP;

    float2 acc = make_float2(0.f, 0.f);
    float ws = 0.f;

    // chunk 0 (covers deg<=8: ~93% of rows)
    {
        int c = deg < 8 ? deg : 8;
        float2 f[8];
#pragma unroll
        for (int t = 0; t < 8; ++t)
            if (t < c) f[t] = feat2[(size_t)nn0[t] * 64 + l];
#pragma unroll
        for (int t = 0; t < 8; ++t)
            if (t < c) {
                acc.x = fmaf(w0[t], f[t].x, acc.x);
                acc.y = fmaf(w0[t], f[t].y, acc.y);
                ws += w0[t];
            }
    }

    // rare tail chunks (deg>8: ~7%); uniform scalar loop, slot reads stay in-bounds
    for (int j = 8; j < deg; j += 8) {
        int c = deg - j;
        if (c > 8) c = 8;
        int nn[8];
        float w[8];
#pragma unroll
        for (int t = 0; t < 8; ++t) {
            int2 pr = srow[j + t];                       // j<=16, j+t<=23 < CAP
            nn[t] = pr.x;
            w[t] = __int_as_float(pr.y);
        }
        float2 f[8];
#pragma unroll
        for (int t = 0; t < 8; ++t)
            if (t < c) f[t] = feat2[(size_t)nn[t] * 64 + l];
#pragma unroll
        for (int t = 0; t < 8; ++t)
            if (t < c) {
                acc.x = fmaf(w[t], f[t].x, acc.x);
                acc.y = fmaf(w[t], f[t].y, acc.y);
                ws += w[t];
            }
    }

    float d = (ws > 0.f) ? ws : 0.001f;
    float inv = 1.0f / d;
    f2v o;
    o.x = acc.x * inv;
    o.y = acc.y * inv;
    // output has zero reuse: bypass cache pollution
    __builtin_nontemporal_store(o, (f2v*)&out2[(size_t)r * 64 + l]);
}

extern "C" void kernel_launch(void* const* d_in, const int* in_sizes, int n_in,
                              void* d_out, int out_size, void* d_ws, size_t ws_size,
                              hipStream_t stream) {
    const float* features = (const float*)d_in[0];
    const float* wdown    = (const float*)d_in[1];
    const int*   nidx     = (const int*)d_in[2];
    const int*   sel      = (const int*)d_in[3];

    int E    = in_sizes[1];            // N*K = 2,000,000
    int n_up = in_sizes[3];            // 100,000
    int F    = out_size / n_up;        // 128
    int N    = in_sizes[0] / F;        // 400,000
    int K    = E / N;                  // 5

    // workspace layout:
    // [cursor N ints][bits ceil(N/32) words]  <- one contiguous memset(0)
    // [slots N*CAP int2]
    int Nb = (N + 31) / 32;
    int* cursor = (int*)d_ws;
    unsigned int* bits = (unsigned int*)(cursor + N);
    size_t zero_bytes = (size_t)N * sizeof(int) + (size_t)Nb * sizeof(unsigned int);
    size_t slots_off = (zero_bytes + 15) & ~(size_t)15;
    int2* slots = (int2*)((char*)d_ws + slots_off);

    (void)hipMemsetAsync(d_ws, 0, zero_bytes, stream);

    mark_kernel<<<(n_up + BLOCK - 1) / BLOCK, BLOCK, 0, stream>>>(sel, bits, n_up);

    int e4 = (E + 3) / 4;
    if (K == 5) {
        fill_kernel<5><<<(e4 + BLOCK - 1) / BLOCK, BLOCK, 0, stream>>>(
            nidx, wdown, bits, cursor, slots, E);
    } else {
        fill_generic_kernel<<<(E + BLOCK - 1) / BLOCK, BLOCK, 0, stream>>>(
            nidx, wdown, bits, cursor, slots, E, K);
    }

    long long threads = (long long)n_up * 64;            // one wave64 per row
    gather_kernel<<<(int)((threads + BLOCK - 1) / BLOCK), BLOCK, 0, stream>>>(
        (const float2*)features, slots, cursor, sel, (float2*)d_out, n_up);
}

// Round 5
// 353.425 us; speedup vs baseline: 1.0396x; 1.0396x over previous
//
#include <hip/hip_runtime.h>

#define BLOCK 256
#define CAP 24   // max stored in-edges per node; in-deg ~ Poisson(5), P(>24) ~ 1e-11

// ---------- mark selected nodes into a BITMASK (50 KB; one line covers 2048 nodes) ----------
__global__ void mark_kernel(const int* __restrict__ sel, unsigned int* __restrict__ bits,
                            int n_up) {
    int u = blockIdx.x * blockDim.x + threadIdx.x;
    if (u < n_up) {
        int v = sel[u];
        atomicOr(&bits[v >> 5], 1u << (v & 31));
    }
}

// ---------- fill node-keyed slots, edge-parallel, vectorized ----------
template <int KK>
__global__ void fill_kernel(const int* __restrict__ nidx, const float* __restrict__ wdown,
                            const unsigned int* __restrict__ bits,
                            int* __restrict__ cursor, int2* __restrict__ slots, int E) {
    int i4 = blockIdx.x * blockDim.x + threadIdx.x;
    int base = i4 * 4;
    if (base + 3 < E) {
        int4 mm = ((const int4*)nidx)[i4];
        float4 ww = ((const float4*)wdown)[i4];
        // issue the 4 independent bitmask word loads up front
        unsigned int b0 = (mm.x >= 0) ? bits[mm.x >> 5] : 0u;
        unsigned int b1 = (mm.y >= 0) ? bits[mm.y >> 5] : 0u;
        unsigned int b2 = (mm.z >= 0) ? bits[mm.z >> 5] : 0u;
        unsigned int b3 = (mm.w >= 0) ? bits[mm.w >> 5] : 0u;
        {
            int m = mm.x;
            if ((b0 >> (m & 31)) & 1u) {
                int n = (base + 0) / KK;  // compile-time KK -> magic mul
                int c = atomicAdd(&cursor[m], 1);
                if (c < CAP) slots[(size_t)m * CAP + c] = make_int2(n, __float_as_int(ww.x));
            }
        }
        {
            int m = mm.y;
            if ((b1 >> (m & 31)) & 1u) {
                int n = (base + 1) / KK;
                int c = atomicAdd(&cursor[m], 1);
                if (c < CAP) slots[(size_t)m * CAP + c] = make_int2(n, __float_as_int(ww.y));
            }
        }
        {
            int m = mm.z;
            if ((b2 >> (m & 31)) & 1u) {
                int n = (base + 2) / KK;
                int c = atomicAdd(&cursor[m], 1);
                if (c < CAP) slots[(size_t)m * CAP + c] = make_int2(n, __float_as_int(ww.z));
            }
        }
        {
            int m = mm.w;
            if ((b3 >> (m & 31)) & 1u) {
                int n = (base + 3) / KK;
                int c = atomicAdd(&cursor[m], 1);
                if (c < CAP) slots[(size_t)m * CAP + c] = make_int2(n, __float_as_int(ww.w));
            }
        }
    } else if (base < E) {
        for (int e = base; e < E; ++e) {
            int m = nidx[e];
            if (m >= 0 && ((bits[m >> 5] >> (m & 31)) & 1u)) {
                int n = e / KK;
                int c = atomicAdd(&cursor[m], 1);
                if (c < CAP) slots[(size_t)m * CAP + c] = make_int2(n, __float_as_int(wdown[e]));
            }
        }
    }
}

// generic-K fallback (runtime division)
__global__ void fill_generic_kernel(const int* __restrict__ nidx, const float* __restrict__ wdown,
                                    const unsigned int* __restrict__ bits,
                                    int* __restrict__ cursor, int2* __restrict__ slots,
                                    int E, int K) {
    int e = blockIdx.x * blockDim.x + threadIdx.x;
    if (e >= E) return;
    int m = nidx[e];
    if (m >= 0 && ((bits[m >> 5] >> (m & 31)) & 1u)) {
        int n = e / K;
        int c = atomicAdd(&cursor[m], 1);
        if (c < CAP) slots[(size_t)m * CAP + c] = make_int2(n, __float_as_int(wdown[e]));
    }
}

// ---------- gather + normalize ----------
// TWO rows per wave64: lanes 0-31 -> row A, lanes 32-63 -> row B.
// One global_load_dwordx4 moves 1024B covering BOTH rows (prev-session memory shape).
// Row ids rA/rB are wave-uniform -> sel/cursor/slot-chunks are SCALAR loads (s_load,
// chunk0 merges to dwordx16); per-half operand select is 2 cndmask VALU ops, no LDS.
__global__ __launch_bounds__(256, 8)
void gather_kernel(const float4* __restrict__ feat4, const int2* __restrict__ slots,
                   const int* __restrict__ cursor, const int* __restrict__ sel,
                   float4* __restrict__ out4, int n_up) {
    int gid = blockIdx.x * blockDim.x + threadIdx.x;
    int wid = gid >> 6;
    int lane = threadIdx.x & 63;
    int half = lane >> 5;
    int l = lane & 31;
    int rA = wid * 2;
    if (rA >= n_up) return;                       // wave-uniform exit
    int hasB = (rA + 1 < n_up);
    int rB = hasB ? rA + 1 : rA;

    int mA = __builtin_amdgcn_readfirstlane(sel[rA]);
    int mB = __builtin_amdgcn_readfirstlane(sel[rB]);
    const int2* __restrict__ srA = slots + (size_t)mA * CAP;
    const int2* __restrict__ srB = slots + (size_t)mB * CAP;

    int degA = cursor[mA];                        // scalar loads, in flight...
    int degB = cursor[mB];
    int nnA[8], nnB[8];
    float wA[8], wB[8];
#pragma unroll
    for (int t = 0; t < 8; ++t) {                 // ...parallel: 2x s_load_dwordx16
        int2 a = srA[t];
        int2 b = srB[t];
        nnA[t] = a.x; wA[t] = __int_as_float(a.y);
        nnB[t] = b.x; wB[t] = __int_as_float(b.y);
    }
    if (degA > CAP) degA = CAP;
    if (degB > CAP) degB = CAP;
    if (!hasB) degB = 0;                          // don't duplicate row A's work
    int deg_v = half ? degB : degA;               // per-lane (uniform per half)
    int degM = degA > degB ? degA : degB;         // scalar loop bound

    float4 acc = make_float4(0.f, 0.f, 0.f, 0.f);
    float ws = 0.f;

    // chunk 0 (covers deg<=8: ~93% of rows)
    {
        int c = deg_v < 8 ? deg_v : 8;
        float4 f[8];
#pragma unroll
        for (int t = 0; t < 8; ++t)
            if (t < c) {
                int nn = half ? nnB[t] : nnA[t];  // cndmask from SGPRs
                f[t] = feat4[(size_t)nn * 32 + l];
            }
#pragma unroll
        for (int t = 0; t < 8; ++t)
            if (t < c) {
                float wt = half ? wB[t] : wA[t];
                acc.x = fmaf(wt, f[t].x, acc.x);
                acc.y = fmaf(wt, f[t].y, acc.y);
                acc.z = fmaf(wt, f[t].z, acc.z);
                acc.w = fmaf(wt, f[t].w, acc.w);
                ws += wt;
            }
    }

    // rare tail chunks (deg>8: ~7%); scalar slot reads stay in-bounds (j+t<=23<CAP)
    for (int j = 8; j < degM; j += 8) {
        int nnA2[8], nnB2[8];
        float wA2[8], wB2[8];
#pragma unroll
        for (int t = 0; t < 8; ++t) {
            int2 a = srA[j + t];
            int2 b = srB[j + t];
            nnA2[t] = a.x; wA2[t] = __int_as_float(a.y);
            nnB2[t] = b.x; wB2[t] = __int_as_float(b.y);
        }
        int c = deg_v - j;
        if (c > 8) c = 8;
        float4 f[8];
#pragma unroll
        for (int t = 0; t < 8; ++t)
            if (t < c) {
                int nn = half ? nnB2[t] : nnA2[t];
                f[t] = feat4[(size_t)nn * 32 + l];
            }
#pragma unroll
        for (int t = 0; t < 8; ++t)
            if (t < c) {
                float wt = half ? wB2[t] : wA2[t];
                acc.x = fmaf(wt, f[t].x, acc.x);
                acc.y = fmaf(wt, f[t].y, acc.y);
                acc.z = fmaf(wt, f[t].z, acc.z);
                acc.w = fmaf(wt, f[t].w, acc.w);
                ws += wt;
            }
    }

    float d = (ws > 0.f) ? ws : 0.001f;
    float inv = 1.0f / d;
    int r = rA + half;
    if (r < n_up)
        out4[(size_t)r * 32 + l] = make_float4(acc.x * inv, acc.y * inv, acc.z * inv, acc.w * inv);
}

extern "C" void kernel_launch(void* const* d_in, const int* in_sizes, int n_in,
                              void* d_out, int out_size, void* d_ws, size_t ws_size,
                              hipStream_t stream) {
    const float* features = (const float*)d_in[0];
    const float* wdown    = (const float*)d_in[1];
    const int*   nidx     = (const int*)d_in[2];
    const int*   sel      = (const int*)d_in[3];

    int E    = in_sizes[1];            // N*K = 2,000,000
    int n_up = in_sizes[3];            // 100,000
    int F    = out_size / n_up;        // 128
    int N    = in_sizes[0] / F;        // 400,000
    int K    = E / N;                  // 5

    // workspace layout:
    // [cursor N ints][bits ceil(N/32) words]  <- one contiguous memset(0)
    // [slots N*CAP int2]
    int Nb = (N + 31) / 32;
    int* cursor = (int*)d_ws;
    unsigned int* bits = (unsigned int*)(cursor + N);
    size_t zero_bytes = (size_t)N * sizeof(int) + (size_t)Nb * sizeof(unsigned int);
    size_t slots_off = (zero_bytes + 15) & ~(size_t)15;
    int2* slots = (int2*)((char*)d_ws + slots_off);

    (void)hipMemsetAsync(d_ws, 0, zero_bytes, stream);

    mark_kernel<<<(n_up + BLOCK - 1) / BLOCK, BLOCK, 0, stream>>>(sel, bits, n_up);

    int e4 = (E + 3) / 4;
    if (K == 5) {
        fill_kernel<5><<<(e4 + BLOCK - 1) / BLOCK, BLOCK, 0, stream>>>(
            nidx, wdown, bits, cursor, slots, E);
    } else {
        fill_generic_kernel<<<(E + BLOCK - 1) / BLOCK, BLOCK, 0, stream>>>(
            nidx, wdown, bits, cursor, slots, E, K);
    }

    long long waves = (n_up + 1) / 2;              // 2 rows per wave64
    long long threads = waves * 64;
    gather_kernel<<<(int)((threads + BLOCK - 1) / BLOCK), BLOCK, 0, stream>>>(
        (const float4*)features, slots, cursor, sel, (float4*)d_out, n_up);
}